// Round 3
// baseline (629.320 us; speedup 1.0000x reference)
//
#include <hip/hip_runtime.h>

// 2-layer GCN forward, gather-based (no float atomics).
// ws layout (4-byte elements):
//   int   cnt_out[10000]      -- out-degree counters
//   int   cnt_in [10000]      -- in-degree counters (double as CSR cursors)
//   int   esrc   [10000*128]  -- per-dst in-edge source lists (capacity 128)
//   float Y1a    [10000*16]   -- GEMM partial, j-segment 0
//   float Y1b    [10000*16]   -- GEMM partial, j-segment 1
//   float H2     [10000*8]    -- layer-2 pre-aggregation (7 used, col 7 = 0)

constexpr int NN  = 10000;
constexpr int NE  = 320000;
constexpr int HID = 16;
constexpr int LAB = 7;
constexpr int CAP = 128;   // max in-degree ~ Poisson(32) -> ~70; 128 is safe

// ---- build counts + capacity-CSR in one pass ----
__global__ void k_count_fill(const int* __restrict__ src, const int* __restrict__ dst,
                             int* __restrict__ cnt_out, int* __restrict__ cnt_in,
                             int* __restrict__ esrc) {
  const int e = blockIdx.x * blockDim.x + threadIdx.x;
  if (e < NE) {
    const int s = src[e], d = dst[e];
    atomicAdd(&cnt_out[s], 1);
    const int p = atomicAdd(&cnt_in[d], 1);
    if (p < CAP) esrc[(d << 7) + p] = s;
  }
}

// ---- Layer-1 GEMM: Y1[row,k] = ns[row] * sum_j F[row,j]*W1[j,k] ----
// grid (625 row-blocks, 2 j-segments of 5000), 256 threads (4 waves x 4 rows).
// W tile transposed in LDS: wT[k*500 + j] -> contiguous (conflict-free) b128
// reads. Wave reduction: exchange-halving (63 shfl_xor total, vs 384 for the
// naive butterfly over 64 accumulators) -> lane l ends owning output elem l,
// giving a fully-coalesced 256 B/wave epilogue store.
__global__ __launch_bounds__(256) void k_gemm1(const float* __restrict__ F,
                                               const float* __restrict__ W1,
                                               const int* __restrict__ cnt_out,
                                               float* __restrict__ Y1a,
                                               float* __restrict__ Y1b) {
  constexpr int BJ = 500;     // j per LDS tile
  constexpr int TILES = 10;   // 10 x 500 = 5000 per segment
  __shared__ float wT[HID * BJ];  // 32000 B
  const int tid  = threadIdx.x;
  const int lane = tid & 63;
  const int wave = tid >> 6;
  const int row0 = blockIdx.x * 16 + wave * 4;
  const int jbase = blockIdx.y * 5000;
  float* __restrict__ Yout = blockIdx.y ? Y1b : Y1a;

  // flat acc: index i = m*16 + k  (m = row within wave, k = hidden col)
  float acc[64];
  #pragma unroll
  for (int i = 0; i < 64; ++i) acc[i] = 0.0f;

  for (int t = 0; t < TILES; ++t) {
    const int jt = jbase + t * BJ;
    __syncthreads();
    // stage W1[jt..jt+500, 0:16] transposed (coalesced float4 global reads,
    // 2-way-free scalar LDS writes)
    for (int u = tid; u < BJ * 4; u += 256) {
      const int j = u >> 2, k4 = u & 3;
      const float4 v = *(const float4*)(W1 + (size_t)(jt + j) * HID + k4 * 4);
      wT[(k4 * 4 + 0) * BJ + j] = v.x;
      wT[(k4 * 4 + 1) * BJ + j] = v.y;
      wT[(k4 * 4 + 2) * BJ + j] = v.z;
      wT[(k4 * 4 + 3) * BJ + j] = v.w;
    }
    __syncthreads();

    const float* Fr = F + (size_t)row0 * NN + jt;
    #pragma unroll
    for (int c = 0; c < 2; ++c) {
      const int j4 = lane + 64 * c;   // float4 index within tile
      if (j4 < BJ / 4) {
        const int j = j4 * 4;
        const float4 f0 = *(const float4*)(Fr + j);
        const float4 f1 = *(const float4*)(Fr + NN + j);
        const float4 f2 = *(const float4*)(Fr + 2 * NN + j);
        const float4 f3 = *(const float4*)(Fr + 3 * NN + j);
        #pragma unroll
        for (int k = 0; k < HID; ++k) {
          const float4 w = *(const float4*)(wT + k * BJ + j);
          acc[0 * 16 + k] = fmaf(f0.x, w.x, fmaf(f0.y, w.y, fmaf(f0.z, w.z, fmaf(f0.w, w.w, acc[0 * 16 + k]))));
          acc[1 * 16 + k] = fmaf(f1.x, w.x, fmaf(f1.y, w.y, fmaf(f1.z, w.z, fmaf(f1.w, w.w, acc[1 * 16 + k]))));
          acc[2 * 16 + k] = fmaf(f2.x, w.x, fmaf(f2.y, w.y, fmaf(f2.z, w.z, fmaf(f2.w, w.w, acc[2 * 16 + k]))));
          acc[3 * 16 + k] = fmaf(f3.x, w.x, fmaf(f3.y, w.y, fmaf(f3.z, w.z, fmaf(f3.w, w.w, acc[3 * 16 + k]))));
        }
      }
    }
  }

  // exchange-halving reduction: after step with bit b, position p holds the
  // partial for logical index whose bit-b equals (lane & b). Final: position 0
  // = full sum over lanes of logical index == lane.
  #pragma unroll
  for (int b = 32; b >= 1; b >>= 1) {
    #pragma unroll
    for (int p = 0; p < 64; ++p) {
      if (p < b) {
        const float lo = acc[p], hi = acc[p + b];
        const bool up = (lane & b) != 0;
        const float send = up ? lo : hi;
        const float keep = up ? hi : lo;
        acc[p] = keep + __shfl_xor(send, b, 64);
      }
    }
  }

  // lane l holds Y[row0 + (l>>4)][l&15]; store is contiguous across the wave
  const int row = row0 + (lane >> 4);
  const float s = rsqrtf(fmaxf((float)cnt_out[row], 1.0f));
  Yout[(size_t)row0 * HID + lane] = acc[0] * s;
}

// ---- Fused layer-1 aggregation + relu + bias + layer-2 transform ----
// one wave per node; 64 lanes = 4 edges x 16 features
__global__ __launch_bounds__(256) void k_gather1(
    const int* __restrict__ cnt_out, const int* __restrict__ cnt_in,
    const int* __restrict__ esrc,
    const float* __restrict__ Y1a, const float* __restrict__ Y1b,
    const float* __restrict__ b1, const float* __restrict__ W2,
    float* __restrict__ H2) {
  __shared__ float hsh[4][16];
  const int tid = threadIdx.x, lane = tid & 63, wave = tid >> 6;
  const int i = blockIdx.x * 4 + wave;       // 2500 blocks x 4 = 10000
  const int n = min(cnt_in[i], CAP);
  const int* el = esrc + ((size_t)i << 7);
  const int sub = lane >> 4, k = lane & 15;
  float sum = 0.0f;
  for (int e = sub; e < n; e += 4) {
    const int s = el[e];                     // broadcast within 16-lane group
    sum += Y1a[s * HID + k] + Y1b[s * HID + k];
  }
  sum += __shfl_down(sum, 32, 64);
  sum += __shfl_down(sum, 16, 64);
  if (lane < 16) {
    const float ndv = rsqrtf(fmaxf((float)n, 1.0f));
    hsh[wave][k] = fmaxf(fmaf(sum, ndv, b1[k]), 0.0f);
  }
  __syncthreads();
  if (lane < 8) {
    float z = 0.0f;
    if (lane < LAB) {
      #pragma unroll
      for (int kk = 0; kk < HID; ++kk)
        z = fmaf(hsh[wave][kk], W2[kk * LAB + lane], z);
      z *= rsqrtf(fmaxf((float)cnt_out[i], 1.0f));
    }
    H2[i * 8 + lane] = z;                    // col 7 written as 0
  }
}

// ---- Fused layer-2 aggregation + epilogue ----
// one wave per node; 64 lanes = 8 edges x 8 label slots
__global__ __launch_bounds__(256) void k_gather2(
    const int* __restrict__ cnt_in, const int* __restrict__ esrc,
    const float* __restrict__ H2, const float* __restrict__ b2,
    float* __restrict__ out) {
  const int tid = threadIdx.x, lane = tid & 63, wave = tid >> 6;
  const int i = blockIdx.x * 4 + wave;
  const int n = min(cnt_in[i], CAP);
  const int* el = esrc + ((size_t)i << 7);
  const int sub = lane >> 3, c = lane & 7;
  float sum = 0.0f;
  for (int e = sub; e < n; e += 8) {
    sum += H2[(el[e] << 3) + c];
  }
  sum += __shfl_down(sum, 32, 64);
  sum += __shfl_down(sum, 16, 64);
  sum += __shfl_down(sum, 8, 64);
  if (lane < LAB) {
    const float ndv = rsqrtf(fmaxf((float)n, 1.0f));
    out[i * LAB + lane] = fmaf(sum, ndv, b2[lane]);
  }
}

extern "C" void kernel_launch(void* const* d_in, const int* in_sizes, int n_in,
                              void* d_out, int out_size, void* d_ws, size_t ws_size,
                              hipStream_t stream) {
  const float* F   = (const float*)d_in[0];
  const int*   src = (const int*)d_in[1];
  const int*   dst = (const int*)d_in[2];
  const float* W1  = (const float*)d_in[3];
  const float* b1  = (const float*)d_in[4];
  const float* W2  = (const float*)d_in[5];
  const float* b2  = (const float*)d_in[6];
  float* out = (float*)d_out;

  int* cnt_out = (int*)d_ws;
  int* cnt_in  = cnt_out + NN;
  int* esrc    = cnt_in + NN;
  float* Y1a   = (float*)(esrc + NN * CAP);
  float* Y1b   = Y1a + NN * HID;
  float* H2    = Y1b + NN * HID;

  hipMemsetAsync(d_ws, 0, 2 * NN * sizeof(int), stream);
  k_count_fill<<<(NE + 255) / 256, 256, 0, stream>>>(src, dst, cnt_out, cnt_in, esrc);
  k_gemm1<<<dim3(625, 2), 256, 0, stream>>>(F, W1, cnt_out, Y1a, Y1b);
  k_gather1<<<NN / 4, 256, 0, stream>>>(cnt_out, cnt_in, esrc, Y1a, Y1b, b1, W2, H2);
  k_gather2<<<NN / 4, 256, 0, stream>>>(cnt_in, esrc, H2, b2, out);
}